// Round 14
// baseline (255.102 us; speedup 1.0000x reference)
//
#include <hip/hip_runtime.h>
#include <hip/hip_fp16.h>

using f32x4  = __attribute__((ext_vector_type(4))) float;
using short8 = __attribute__((ext_vector_type(8))) short;

#define LOG2E 1.4426950408889634f

static __device__ __forceinline__ unsigned short f2bf(float f) {
  union { float f; unsigned u; } c; c.f = f;
  unsigned u = c.u;
  return (unsigned short)((u + 0x7fffu + ((u >> 16) & 1u)) >> 16);  // RNE
}
static __device__ __forceinline__ float bf2f(unsigned short b) {
  union { unsigned u; float f; } c; c.u = ((unsigned)b) << 16;
  return c.f;
}

// W transpose (-> bf16 wt[col][k], 32KB L2-resident) + deg zeroing fused.
__global__ __launch_bounds__(256) void k_wz(const float* __restrict__ W,
                                            unsigned short* __restrict__ wt,
                                            int* __restrict__ deg, int N) {
  int idx = blockIdx.x * 256 + threadIdx.x;
  if (idx < 16384) {
    int hh = idx >> 12, i = (idx >> 5) & 127, o = idx & 31;
    wt[(hh * 32 + o) * 128 + i] = f2bf(W[idx]);
  }
  for (int j = idx; j < N; j += gridDim.x * 256) deg[j] = 0;
}

// ---- fused gemm + prep, uniform blocks. Each block: one 64-row gemm tile,
// then grid-strided 256-edge prep chunks. No LDS (wt from L1/L2).
// src32/dst32 live in d_ws (NOT d_out: aliasing d_out while k_gather also
// writes it raced via cross-XCD L2 dirty lines -> R13 post-timing corruption).
__global__ __launch_bounds__(256) void k_gp(const float* __restrict__ x,
                                            const unsigned short* __restrict__ wt,
                                            const float* __restrict__ a,
                                            const void* __restrict__ ei,
                                            unsigned short* __restrict__ hbf,
                                            float* __restrict__ ssrc,
                                            float* __restrict__ sdst,
                                            int* __restrict__ src32,
                                            int* __restrict__ dst32,
                                            int* __restrict__ deg,
                                            int nnodes, int E) {
  __shared__ int sh_is64;
  const int tid = threadIdx.x;

  // int64-vs-int32 detection, once per block (wave 0 ballot)
  if (tid < 64) {
    long long v = ((const long long*)ei)[tid];
    int ok = (v >= 0 && v < (long long)nnodes) ? 1 : 0;
    unsigned long long m = __ballot(ok);
    if (tid == 0) sh_is64 = (m == ~0ull) ? 1 : 0;
  }
  __syncthreads();

  // ---------------- GEMM tile ----------------
  {
    const int n0 = blockIdx.x * 64;
    const int wave = tid >> 6, lane = tid & 63;
    const int m0 = wave * 16;
    const int lr = lane & 15, lh = lane >> 4;
    const int n = n0 + m0 + lr;          // row this lane's A-fragment comes from
    const bool rowok = n < nnodes;
    const float* xrow = x + (size_t)n * 128;

    short8 avf[4];
#pragma unroll
    for (int kk = 0; kk < 4; ++kk) {
      float4 u0 = make_float4(0.f, 0.f, 0.f, 0.f), u1 = u0;
      if (rowok) {
        u0 = *(const float4*)(xrow + kk * 32 + lh * 8);
        u1 = *(const float4*)(xrow + kk * 32 + lh * 8 + 4);
      }
      short8 v;
      v[0] = (short)f2bf(u0.x); v[1] = (short)f2bf(u0.y);
      v[2] = (short)f2bf(u0.z); v[3] = (short)f2bf(u0.w);
      v[4] = (short)f2bf(u1.x); v[5] = (short)f2bf(u1.y);
      v[6] = (short)f2bf(u1.z); v[7] = (short)f2bf(u1.w);
      avf[kk] = v;
    }

    f32x4 acc[8] = {};
#pragma unroll
    for (int kk = 0; kk < 4; ++kk) {
#pragma unroll
      for (int f = 0; f < 8; ++f) {
        short8 bv = *(const short8*)(wt + (f * 16 + lr) * 128 + kk * 32 + lh * 8);
        acc[f] = __builtin_amdgcn_mfma_f32_16x16x32_bf16(avf[kk], bv, acc[f], 0, 0, 0);
      }
    }

    float avc[4][4];
#pragma unroll
    for (int hh = 0; hh < 4; ++hh) {
      avc[hh][0] = a[hh * 64 + lr];
      avc[hh][1] = a[hh * 64 + 16 + lr];
      avc[hh][2] = a[hh * 64 + 32 + lr];
      avc[hh][3] = a[hh * 64 + 48 + lr];
    }

#pragma unroll
    for (int j = 0; j < 4; ++j) {
      int nn = n0 + m0 + lh * 4 + j;
#pragma unroll
      for (int f = 0; f < 8; ++f) {
        if (nn < nnodes) hbf[(size_t)nn * 128 + f * 16 + lr] = f2bf(acc[f][j]);
      }
#pragma unroll
      for (int hh = 0; hh < 4; ++hh) {
        float s0 = acc[2 * hh][j] * avc[hh][0] + acc[2 * hh + 1][j] * avc[hh][1];
        float s1 = acc[2 * hh][j] * avc[hh][2] + acc[2 * hh + 1][j] * avc[hh][3];
#pragma unroll
        for (int m = 1; m < 16; m <<= 1) {
          s0 += __shfl_xor(s0, m);
          s1 += __shfl_xor(s1, m);
        }
        if (lr == hh && nn < nnodes) {
          ssrc[(size_t)nn * 4 + hh] = s0 * LOG2E;   // pre-scaled for exp2
          sdst[(size_t)nn * 4 + hh] = s1 * LOG2E;
        }
      }
    }
  }

  // ---------------- PREP (grid-strided edge chunks) ----------------
  const int is64 = sh_is64;
  const int stride = gridDim.x * 256;
  for (int e0 = blockIdx.x * 256; e0 < E; e0 += stride) {
    int e = e0 + tid;
    if (e < E) {
      int s, d;
      if (is64) {
        s = (int)((const long long*)ei)[e];
        d = (int)((const long long*)ei)[(size_t)E + e];
      } else {
        s = ((const int*)ei)[e];
        d = ((const int*)ei)[(size_t)E + e];
      }
      src32[e] = s;
      dst32[e] = d;
      atomicAdd(&deg[d], 1);
    }
  }
}

__global__ __launch_bounds__(256) void k_scan1(const int* __restrict__ deg, int* __restrict__ rowstart,
                                               int* __restrict__ bsum, int N) {
  __shared__ int l[256];
  int t = threadIdx.x;
  int gid = blockIdx.x * 256 + t;
  int v = (gid < N) ? deg[gid] : 0;
  l[t] = v;
  __syncthreads();
  for (int off = 1; off < 256; off <<= 1) {
    int u = (t >= off) ? l[t - off] : 0;
    __syncthreads();
    l[t] += u;
    __syncthreads();
  }
  if (gid < N) rowstart[gid] = l[t] - v;     // exclusive within block
  if (t == 255) bsum[blockIdx.x] = l[255];   // RAW block sum
}

// scan3 computes the bsum prefix itself (no scan2): 256 threads stride-sum
// bsum[0..blockIdx), wave butterfly + LDS reduce, add to local scan.
__global__ __launch_bounds__(256) void k_scan3(int* __restrict__ rowstart, const int* __restrict__ bsum,
                                               int* __restrict__ cursor, int N) {
  __shared__ int red[4];
  int t = threadIdx.x;
  int part = 0;
  for (int i = t; i < blockIdx.x; i += 256) part += bsum[i];
#pragma unroll
  for (int m = 1; m < 64; m <<= 1) part += __shfl_xor(part, m);
  if ((t & 63) == 0) red[t >> 6] = part;
  __syncthreads();
  int off = red[0] + red[1] + red[2] + red[3];
  int gid = blockIdx.x * 256 + t;
  if (gid < N) {
    int r = rowstart[gid] + off;
    rowstart[gid] = r;
    cursor[gid] = r;
  }
}

// Partitioned scatter, eidx ONLY (R4-proven: 0.8MB/XCD write window -> no
// write amplification). Partition count MUST equal 8 (XCD count).
__global__ __launch_bounds__(256) void k_scatter(const int* __restrict__ src32,
                                                 const int* __restrict__ dst32,
                                                 int* __restrict__ cursor,
                                                 int* __restrict__ eidx, int E, int N) {
  const int part = blockIdx.x & 7;
  const int wblk = blockIdx.x >> 3;
  const int nwb = gridDim.x >> 3;
  const int lo = (int)(((long long)N * part) >> 3);
  const int hi = (int)(((long long)N * (part + 1)) >> 3);
  for (int e = wblk * 256 + threadIdx.x; e < E; e += nwb * 256) {
    int d = dst32[e];
    if (d >= lo && d < hi) {
      int pos = atomicAdd(&cursor[d], 1);
      eidx[pos] = src32[e];
    }
  }
}

// ---- gather: one wave per dst; bf16 h; p computed once per (edge,head) on
// lanes 0-31 and broadcast via shfl; 8-deep MLP. Plain stores (NT stores +
// multi-writer d_out raced -> R13 corruption; keep the write path coherent).
__global__ __launch_bounds__(256) void k_gather(const unsigned short* __restrict__ hbf,
                                                const int* __restrict__ rowstart,
                                                const int* __restrict__ deg,
                                                const int* __restrict__ eidx,
                                                const float* __restrict__ ssrc,
                                                const float* __restrict__ sdst,
                                                float* __restrict__ out, int N) {
  int wid = (blockIdx.x * 256 + threadIdx.x) >> 6;
  int lane = threadIdx.x & 63;
  if (wid >= N) return;
  const int dst = wid;
  const int beg = rowstart[dst];
  const int end = beg + deg[dst];
  const int hh = lane >> 4;              // head of this lane's col pair
  const int lq = lane & 3;               // p-compute: head index
  const int le = lane >> 2;              // p-compute: edge offset within group
  const float sdP = sdst[(size_t)dst * 4 + lq];
  const float sdH = sdst[(size_t)dst * 4 + hh];
  const unsigned* __restrict__ h32 = (const unsigned*)hbf;
  float acc0 = 0.f, acc1 = 0.f, ps = 0.f;

  int i = beg;
  for (; i + 7 < end; i += 8) {
    int s0 = eidx[i + 0], s1 = eidx[i + 1], s2 = eidx[i + 2], s3 = eidx[i + 3];
    int s4 = eidx[i + 4], s5 = eidx[i + 5], s6 = eidx[i + 6], s7 = eidx[i + 7];
    int ip = i + le; ip = (ip < end) ? ip : (end - 1);
    int sP = eidx[ip];
    float ev = ssrc[(size_t)sP * 4 + lq] + sdP;
    ev = fmaxf(ev, 0.2f * ev);
    float pv = exp2f(ev);
    unsigned hv0 = h32[((unsigned)s0 << 6) | (unsigned)lane];
    unsigned hv1 = h32[((unsigned)s1 << 6) | (unsigned)lane];
    unsigned hv2 = h32[((unsigned)s2 << 6) | (unsigned)lane];
    unsigned hv3 = h32[((unsigned)s3 << 6) | (unsigned)lane];
    unsigned hv4 = h32[((unsigned)s4 << 6) | (unsigned)lane];
    unsigned hv5 = h32[((unsigned)s5 << 6) | (unsigned)lane];
    unsigned hv6 = h32[((unsigned)s6 << 6) | (unsigned)lane];
    unsigned hv7 = h32[((unsigned)s7 << 6) | (unsigned)lane];
    float p0 = __shfl(pv, (0 << 2) | hh);
    float p1 = __shfl(pv, (1 << 2) | hh);
    float p2 = __shfl(pv, (2 << 2) | hh);
    float p3 = __shfl(pv, (3 << 2) | hh);
    float p4 = __shfl(pv, (4 << 2) | hh);
    float p5 = __shfl(pv, (5 << 2) | hh);
    float p6 = __shfl(pv, (6 << 2) | hh);
    float p7 = __shfl(pv, (7 << 2) | hh);
    acc0 += p0 * bf2f((unsigned short)(hv0 & 0xffff));
    acc1 += p0 * bf2f((unsigned short)(hv0 >> 16));
    acc0 += p1 * bf2f((unsigned short)(hv1 & 0xffff));
    acc1 += p1 * bf2f((unsigned short)(hv1 >> 16));
    acc0 += p2 * bf2f((unsigned short)(hv2 & 0xffff));
    acc1 += p2 * bf2f((unsigned short)(hv2 >> 16));
    acc0 += p3 * bf2f((unsigned short)(hv3 & 0xffff));
    acc1 += p3 * bf2f((unsigned short)(hv3 >> 16));
    acc0 += p4 * bf2f((unsigned short)(hv4 & 0xffff));
    acc1 += p4 * bf2f((unsigned short)(hv4 >> 16));
    acc0 += p5 * bf2f((unsigned short)(hv5 & 0xffff));
    acc1 += p5 * bf2f((unsigned short)(hv5 >> 16));
    acc0 += p6 * bf2f((unsigned short)(hv6 & 0xffff));
    acc1 += p6 * bf2f((unsigned short)(hv6 >> 16));
    acc0 += p7 * bf2f((unsigned short)(hv7 & 0xffff));
    acc1 += p7 * bf2f((unsigned short)(hv7 >> 16));
    ps += ((p0 + p1) + (p2 + p3)) + ((p4 + p5) + (p6 + p7));
  }
  for (; i < end; ++i) {
    int s = eidx[i];
    unsigned hv = h32[((unsigned)s << 6) | (unsigned)lane];
    float ev = ssrc[(size_t)s * 4 + hh] + sdH;
    ev = fmaxf(ev, 0.2f * ev);
    float p = exp2f(ev);
    acc0 += p * bf2f((unsigned short)(hv & 0xffff));
    acc1 += p * bf2f((unsigned short)(hv >> 16));
    ps += p;
  }
  float r = (ps > 0.f) ? 1.f / ps : 0.f;
  out[(size_t)dst * 128 + lane * 2]     = acc0 * r;
  out[(size_t)dst * 128 + lane * 2 + 1] = acc1 * r;
}

extern "C" void kernel_launch(void* const* d_in, const int* in_sizes, int n_in,
                              void* d_out, int out_size, void* d_ws, size_t ws_size,
                              hipStream_t stream) {
  const float* x = (const float*)d_in[0];
  const void*  ei = d_in[1];
  const float* W = (const float*)d_in[2];
  const float* a = (const float*)d_in[3];
  float* out = (float*)d_out;

  const int N = in_sizes[0] / 128;
  const int E = in_sizes[1] / 2;
  const int NB = (N + 255) / 256;              // scan blocks (<=512)
  const int NG = (N + 63) / 64;                // gemm/fused blocks

  char* ws = (char*)d_ws;
  unsigned short* hbf = (unsigned short*)ws;             ws += (size_t)N * 128 * 2;
  unsigned short* wt  = (unsigned short*)ws;             ws += 16384 * 2;
  float* ssrc     = (float*)ws;                          ws += (size_t)N * 4 * 4;
  float* sdst     = (float*)ws;                          ws += (size_t)N * 4 * 4;
  int*   deg      = (int*)ws;                            ws += (size_t)N * 4;
  int*   rowstart = (int*)ws;                            ws += (size_t)N * 4;
  int*   cursor   = (int*)ws;                            ws += (size_t)N * 4;
  int*   bsum     = (int*)ws;                            ws += 512 * 4;
  int*   eidx     = (int*)ws;                            ws += (size_t)E * 4;
  int*   src32    = (int*)ws;                            ws += (size_t)E * 4;
  int*   dst32    = (int*)ws;

  k_wz<<<NB, 256, 0, stream>>>(W, wt, deg, N);
  k_gp<<<NG, 256, 0, stream>>>(x, wt, a, ei, hbf, ssrc, sdst, src32, dst32, deg, N, E);
  k_scan1<<<NB, 256, 0, stream>>>(deg, rowstart, bsum, N);
  k_scan3<<<NB, 256, 0, stream>>>(rowstart, bsum, cursor, N);
  k_scatter<<<2048, 256, 0, stream>>>(src32, dst32, cursor, eidx, E, N);
  k_gather<<<(N + 3) / 4, 256, 0, stream>>>(hbf, rowstart, deg, eidx, ssrc, sdst, out, N);
}

// Round 15
// 246.696 us; speedup vs baseline: 1.0341x; 1.0341x over previous
//
#include <hip/hip_runtime.h>
#include <hip/hip_fp16.h>

using f32x4  = __attribute__((ext_vector_type(4))) float;
using short8 = __attribute__((ext_vector_type(8))) short;
using ushort8 = __attribute__((ext_vector_type(8))) unsigned short;

#define LOG2E 1.4426950408889634f
#define TP 136  // LDS transpose pitch (ushorts)

static __device__ __forceinline__ unsigned short f2bf(float f) {
  union { float f; unsigned u; } c; c.f = f;
  unsigned u = c.u;
  return (unsigned short)((u + 0x7fffu + ((u >> 16) & 1u)) >> 16);  // RNE
}
static __device__ __forceinline__ float bf2f(unsigned short b) {
  union { unsigned u; float f; } c; c.u = ((unsigned)b) << 16;
  return c.f;
}

// W transpose (-> bf16 wt[col][k], 32KB L2-resident) + deg zeroing fused.
__global__ __launch_bounds__(256) void k_wz(const float* __restrict__ W,
                                            unsigned short* __restrict__ wt,
                                            int* __restrict__ deg, int N) {
  int idx = blockIdx.x * 256 + threadIdx.x;
  if (idx < 16384) {
    int hh = idx >> 12, i = (idx >> 5) & 127, o = idx & 31;
    wt[(hh * 32 + o) * 128 + i] = f2bf(W[idx]);
  }
  for (int j = idx; j < N; j += gridDim.x * 256) deg[j] = 0;
}

// ---- fused gemm + prep, 1:4 role-interleave (R12-proven overlap; R14's
// uniform blocks serialized the phases chip-wide). GEMM epilogue stages the
// tile in LDS and stores 16B-coalesced (the old path issued 32x 2B scattered
// stores/thread = 12.8M insts + L2 partial-line churn).
__global__ __launch_bounds__(256) void k_gp(const float* __restrict__ x,
                                            const unsigned short* __restrict__ wt,
                                            const float* __restrict__ a,
                                            const void* __restrict__ ei,
                                            unsigned short* __restrict__ hbf,
                                            float* __restrict__ ssrc,
                                            float* __restrict__ sdst,
                                            int* __restrict__ src32,
                                            int* __restrict__ dst32,
                                            int* __restrict__ deg,
                                            int nnodes, int E, int NG) {
  __shared__ __align__(16) unsigned short tr[64 * TP];  // gemm-role transpose
  __shared__ int sh_is64;
  const int tid = threadIdx.x;
  const unsigned bI = blockIdx.x;

  // role mapping: blockIdx = 5q+r -> r==0: gemm bid q ; r>0: prep bid 4q+r-1.
  int gemm_bid = -1, prep_bid;
  if (bI < 5u * (unsigned)NG) {
    unsigned q = bI / 5u, r = bI % 5u;
    if (r == 0) gemm_bid = (int)q;
    prep_bid = (int)(4u * q + r - 1u);
  } else {
    prep_bid = (int)(4u * (unsigned)NG + (bI - 5u * (unsigned)NG));
  }

  if (gemm_bid >= 0) {
    // ---------------- GEMM role ----------------
    const int n0 = gemm_bid * 64;
    const int wave = tid >> 6, lane = tid & 63;
    const int m0 = wave * 16;
    const int lr = lane & 15, lh = lane >> 4;
    const int n = n0 + m0 + lr;
    const bool rowok = n < nnodes;
    const float* xrow = x + (size_t)n * 128;

    short8 avf[4];
#pragma unroll
    for (int kk = 0; kk < 4; ++kk) {
      float4 u0 = make_float4(0.f, 0.f, 0.f, 0.f), u1 = u0;
      if (rowok) {
        u0 = *(const float4*)(xrow + kk * 32 + lh * 8);
        u1 = *(const float4*)(xrow + kk * 32 + lh * 8 + 4);
      }
      short8 v;
      v[0] = (short)f2bf(u0.x); v[1] = (short)f2bf(u0.y);
      v[2] = (short)f2bf(u0.z); v[3] = (short)f2bf(u0.w);
      v[4] = (short)f2bf(u1.x); v[5] = (short)f2bf(u1.y);
      v[6] = (short)f2bf(u1.z); v[7] = (short)f2bf(u1.w);
      avf[kk] = v;
    }

    f32x4 acc[8] = {};
#pragma unroll
    for (int kk = 0; kk < 4; ++kk) {
#pragma unroll
      for (int f = 0; f < 8; ++f) {
        short8 bv = *(const short8*)(wt + (f * 16 + lr) * 128 + kk * 32 + lh * 8);
        acc[f] = __builtin_amdgcn_mfma_f32_16x16x32_bf16(avf[kk], bv, acc[f], 0, 0, 0);
      }
    }

    // stage tile into LDS (2B writes are cheap there)
#pragma unroll
    for (int j = 0; j < 4; ++j) {
      int rr = m0 + lh * 4 + j;
#pragma unroll
      for (int f = 0; f < 8; ++f) tr[rr * TP + f * 16 + lr] = f2bf(acc[f][j]);
    }

    // attention scalars (overlaps LDS latency)
    float avc[4][4];
#pragma unroll
    for (int hh = 0; hh < 4; ++hh) {
      avc[hh][0] = a[hh * 64 + lr];
      avc[hh][1] = a[hh * 64 + 16 + lr];
      avc[hh][2] = a[hh * 64 + 32 + lr];
      avc[hh][3] = a[hh * 64 + 48 + lr];
    }
#pragma unroll
    for (int j = 0; j < 4; ++j) {
      int nn = n0 + m0 + lh * 4 + j;
#pragma unroll
      for (int hh = 0; hh < 4; ++hh) {
        float s0 = acc[2 * hh][j] * avc[hh][0] + acc[2 * hh + 1][j] * avc[hh][1];
        float s1 = acc[2 * hh][j] * avc[hh][2] + acc[2 * hh + 1][j] * avc[hh][3];
#pragma unroll
        for (int m = 1; m < 16; m <<= 1) {
          s0 += __shfl_xor(s0, m);
          s1 += __shfl_xor(s1, m);
        }
        if (lr == hh && nn < nnodes) {
          ssrc[(size_t)nn * 4 + hh] = s0 * LOG2E;
          sdst[(size_t)nn * 4 + hh] = s1 * LOG2E;
        }
      }
    }

    __syncthreads();
    // coalesced 16B copies: 64 rows x 16 chunks of 8 ushorts
#pragma unroll
    for (int it = 0; it < 4; ++it) {
      int idx = tid + it * 256;
      int r = idx >> 4, c16 = idx & 15;
      int nn = n0 + r;
      if (nn < nnodes)
        *(ushort8*)(hbf + (size_t)nn * 128 + c16 * 8) = *(const ushort8*)&tr[r * TP + c16 * 8];
    }
  } else {
    // ---------------- PREP role ----------------
    if (tid < 64) {
      long long v = ((const long long*)ei)[tid];
      int ok = (v >= 0 && v < (long long)nnodes) ? 1 : 0;
      unsigned long long m = __ballot(ok);
      if (tid == 0) sh_is64 = (m == ~0ull) ? 1 : 0;
    }
    __syncthreads();
    const int is64 = sh_is64;
    int e = prep_bid * 256 + tid;
    if (e < E) {
      int s, d;
      if (is64) {
        s = (int)((const long long*)ei)[e];
        d = (int)((const long long*)ei)[(size_t)E + e];
      } else {
        s = ((const int*)ei)[e];
        d = ((const int*)ei)[(size_t)E + e];
      }
      src32[e] = s;
      dst32[e] = d;
      atomicAdd(&deg[d], 1);
    }
  }
}

__global__ __launch_bounds__(256) void k_scan1(const int* __restrict__ deg, int* __restrict__ rowstart,
                                               int* __restrict__ bsum, int N) {
  __shared__ int l[256];
  int t = threadIdx.x;
  int gid = blockIdx.x * 256 + t;
  int v = (gid < N) ? deg[gid] : 0;
  l[t] = v;
  __syncthreads();
  for (int off = 1; off < 256; off <<= 1) {
    int u = (t >= off) ? l[t - off] : 0;
    __syncthreads();
    l[t] += u;
    __syncthreads();
  }
  if (gid < N) rowstart[gid] = l[t] - v;
  if (t == 255) bsum[blockIdx.x] = l[255];
}

// scan3 computes the bsum prefix itself (no scan2).
__global__ __launch_bounds__(256) void k_scan3(int* __restrict__ rowstart, const int* __restrict__ bsum,
                                               int* __restrict__ cursor, int N) {
  __shared__ int red[4];
  int t = threadIdx.x;
  int part = 0;
  for (int i = t; i < blockIdx.x; i += 256) part += bsum[i];
#pragma unroll
  for (int m = 1; m < 64; m <<= 1) part += __shfl_xor(part, m);
  if ((t & 63) == 0) red[t >> 6] = part;
  __syncthreads();
  int off = red[0] + red[1] + red[2] + red[3];
  int gid = blockIdx.x * 256 + t;
  if (gid < N) {
    int r = rowstart[gid] + off;
    rowstart[gid] = r;
    cursor[gid] = r;
  }
}

// Partitioned scatter, eidx ONLY (0.8MB/XCD write window -> no write amp).
__global__ __launch_bounds__(256) void k_scatter(const int* __restrict__ src32,
                                                 const int* __restrict__ dst32,
                                                 int* __restrict__ cursor,
                                                 int* __restrict__ eidx, int E, int N) {
  const int part = blockIdx.x & 7;
  const int wblk = blockIdx.x >> 3;
  const int nwb = gridDim.x >> 3;
  const int lo = (int)(((long long)N * part) >> 3);
  const int hi = (int)(((long long)N * (part + 1)) >> 3);
  for (int e = wblk * 256 + threadIdx.x; e < E; e += nwb * 256) {
    int d = dst32[e];
    if (d >= lo && d < hi) {
      int pos = atomicAdd(&cursor[d], 1);
      eidx[pos] = src32[e];
    }
  }
}

// ---- gather: one wave per dst; bf16 h; p computed once per (edge,head) on
// lanes 0-31 and broadcast via shfl; 8-deep MLP. Plain stores only.
__global__ __launch_bounds__(256) void k_gather(const unsigned short* __restrict__ hbf,
                                                const int* __restrict__ rowstart,
                                                const int* __restrict__ deg,
                                                const int* __restrict__ eidx,
                                                const float* __restrict__ ssrc,
                                                const float* __restrict__ sdst,
                                                float* __restrict__ out, int N) {
  int wid = (blockIdx.x * 256 + threadIdx.x) >> 6;
  int lane = threadIdx.x & 63;
  if (wid >= N) return;
  const int dst = wid;
  const int beg = rowstart[dst];
  const int end = beg + deg[dst];
  const int hh = lane >> 4;
  const int lq = lane & 3;
  const int le = lane >> 2;
  const float sdP = sdst[(size_t)dst * 4 + lq];
  const float sdH = sdst[(size_t)dst * 4 + hh];
  const unsigned* __restrict__ h32 = (const unsigned*)hbf;
  float acc0 = 0.f, acc1 = 0.f, ps = 0.f;

  int i = beg;
  for (; i + 7 < end; i += 8) {
    int s0 = eidx[i + 0], s1 = eidx[i + 1], s2 = eidx[i + 2], s3 = eidx[i + 3];
    int s4 = eidx[i + 4], s5 = eidx[i + 5], s6 = eidx[i + 6], s7 = eidx[i + 7];
    int ip = i + le; ip = (ip < end) ? ip : (end - 1);
    int sP = eidx[ip];
    float ev = ssrc[(size_t)sP * 4 + lq] + sdP;
    ev = fmaxf(ev, 0.2f * ev);
    float pv = exp2f(ev);
    unsigned hv0 = h32[((unsigned)s0 << 6) | (unsigned)lane];
    unsigned hv1 = h32[((unsigned)s1 << 6) | (unsigned)lane];
    unsigned hv2 = h32[((unsigned)s2 << 6) | (unsigned)lane];
    unsigned hv3 = h32[((unsigned)s3 << 6) | (unsigned)lane];
    unsigned hv4 = h32[((unsigned)s4 << 6) | (unsigned)lane];
    unsigned hv5 = h32[((unsigned)s5 << 6) | (unsigned)lane];
    unsigned hv6 = h32[((unsigned)s6 << 6) | (unsigned)lane];
    unsigned hv7 = h32[((unsigned)s7 << 6) | (unsigned)lane];
    float p0 = __shfl(pv, (0 << 2) | hh);
    float p1 = __shfl(pv, (1 << 2) | hh);
    float p2 = __shfl(pv, (2 << 2) | hh);
    float p3 = __shfl(pv, (3 << 2) | hh);
    float p4 = __shfl(pv, (4 << 2) | hh);
    float p5 = __shfl(pv, (5 << 2) | hh);
    float p6 = __shfl(pv, (6 << 2) | hh);
    float p7 = __shfl(pv, (7 << 2) | hh);
    acc0 += p0 * bf2f((unsigned short)(hv0 & 0xffff));
    acc1 += p0 * bf2f((unsigned short)(hv0 >> 16));
    acc0 += p1 * bf2f((unsigned short)(hv1 & 0xffff));
    acc1 += p1 * bf2f((unsigned short)(hv1 >> 16));
    acc0 += p2 * bf2f((unsigned short)(hv2 & 0xffff));
    acc1 += p2 * bf2f((unsigned short)(hv2 >> 16));
    acc0 += p3 * bf2f((unsigned short)(hv3 & 0xffff));
    acc1 += p3 * bf2f((unsigned short)(hv3 >> 16));
    acc0 += p4 * bf2f((unsigned short)(hv4 & 0xffff));
    acc1 += p4 * bf2f((unsigned short)(hv4 >> 16));
    acc0 += p5 * bf2f((unsigned short)(hv5 & 0xffff));
    acc1 += p5 * bf2f((unsigned short)(hv5 >> 16));
    acc0 += p6 * bf2f((unsigned short)(hv6 & 0xffff));
    acc1 += p6 * bf2f((unsigned short)(hv6 >> 16));
    acc0 += p7 * bf2f((unsigned short)(hv7 & 0xffff));
    acc1 += p7 * bf2f((unsigned short)(hv7 >> 16));
    ps += ((p0 + p1) + (p2 + p3)) + ((p4 + p5) + (p6 + p7));
  }
  for (; i < end; ++i) {
    int s = eidx[i];
    unsigned hv = h32[((unsigned)s << 6) | (unsigned)lane];
    float ev = ssrc[(size_t)s * 4 + hh] + sdH;
    ev = fmaxf(ev, 0.2f * ev);
    float p = exp2f(ev);
    acc0 += p * bf2f((unsigned short)(hv & 0xffff));
    acc1 += p * bf2f((unsigned short)(hv >> 16));
    ps += p;
  }
  float r = (ps > 0.f) ? 1.f / ps : 0.f;
  out[(size_t)dst * 128 + lane * 2]     = acc0 * r;
  out[(size_t)dst * 128 + lane * 2 + 1] = acc1 * r;
}

extern "C" void kernel_launch(void* const* d_in, const int* in_sizes, int n_in,
                              void* d_out, int out_size, void* d_ws, size_t ws_size,
                              hipStream_t stream) {
  const float* x = (const float*)d_in[0];
  const void*  ei = d_in[1];
  const float* W = (const float*)d_in[2];
  const float* a = (const float*)d_in[3];
  float* out = (float*)d_out;

  const int N = in_sizes[0] / 128;
  const int E = in_sizes[1] / 2;
  const int NB = (N + 255) / 256;
  const int NG = (N + 63) / 64;
  const int NP = (E + 255) / 256;
  const int extra = (NP > 4 * NG) ? (NP - 4 * NG) : 0;
  const int TOT = 5 * NG + extra;

  char* ws = (char*)d_ws;
  unsigned short* hbf = (unsigned short*)ws;             ws += (size_t)N * 128 * 2;
  unsigned short* wt  = (unsigned short*)ws;             ws += 16384 * 2;
  float* ssrc     = (float*)ws;                          ws += (size_t)N * 4 * 4;
  float* sdst     = (float*)ws;                          ws += (size_t)N * 4 * 4;
  int*   deg      = (int*)ws;                            ws += (size_t)N * 4;
  int*   rowstart = (int*)ws;                            ws += (size_t)N * 4;
  int*   cursor   = (int*)ws;                            ws += (size_t)N * 4;
  int*   bsum     = (int*)ws;                            ws += 512 * 4;
  int*   eidx     = (int*)ws;                            ws += (size_t)E * 4;
  int*   src32    = (int*)ws;                            ws += (size_t)E * 4;
  int*   dst32    = (int*)ws;

  k_wz<<<NB, 256, 0, stream>>>(W, wt, deg, N);
  k_gp<<<TOT, 256, 0, stream>>>(x, wt, a, ei, hbf, ssrc, sdst, src32, dst32, deg, N, E, NG);
  k_scan1<<<NB, 256, 0, stream>>>(deg, rowstart, bsum, N);
  k_scan3<<<NB, 256, 0, stream>>>(rowstart, bsum, cursor, N);
  k_scatter<<<2048, 256, 0, stream>>>(src32, dst32, cursor, eidx, E, N);
  k_gather<<<(N + 3) / 4, 256, 0, stream>>>(hbf, rowstart, deg, eidx, ssrc, sdst, out, N);
}